// Round 11
// baseline (2536.035 us; speedup 1.0000x reference)
//
#include <hip/hip_runtime.h>
#include <stdint.h>

typedef _Float16 f16x8 __attribute__((ext_vector_type(8)));
typedef unsigned short u16x8 __attribute__((ext_vector_type(8)));
typedef float f32x4 __attribute__((ext_vector_type(4)));
typedef unsigned int u32x4 __attribute__((ext_vector_type(4)));

#define MFMA16(a,b,c) __builtin_amdgcn_mfma_f32_16x16x32_f16((a),(b),(c),0,0,0)
#define F16(v) __builtin_bit_cast(f16x8, (v))

// problem dims
#define LSEQ 256
#define H0N  269
#define H1N  179
#define H0P  272
#define H1P  192
#define K0REAL 333
#define K1REAL 448
#define K2REAL 243
#define KK0  11    // cell0 K padded to 352 ([x64|h:272pad] + 16 zero)
#define KK1  15    // cell1 K padded to 480 ([a:272|b:192pad] + 16 zero)
#define KK2  8     // cell2 [b:192|c:64]
#define XH2S 200
#define MR   32

// ws layout per group (bytes)
#define H0_OFF   0
#define H0_SLOT  (MR*H0P*2)            // 17408
#define H1_OFF   (8*H0_SLOT)           // 139264
#define H1_SLOT  (MR*H1P*2)            // 12288
#define C2_OFF   (H1_OFF + 8*H1_SLOT)  // 237568 (c_{-1} init slot)
#define CNT_OFF  (C2_OFF + 4096)       // guard flags (33 words used)
#define GSTRIDE  262144

#define BIGNEG   (-(1<<28))
#define NQ2 3

__device__ __forceinline__ unsigned short f2h_bits(float v) {
  return __builtin_bit_cast(unsigned short, (_Float16)v);
}
__device__ __forceinline__ float rcpf(float x) { return __builtin_amdgcn_rcpf(x); }
__device__ __forceinline__ float fast_sig(float s) { return rcpf(1.f + __expf(-s)); }
__device__ __forceinline__ float fast_tanh(float x) {
  float e = __expf(2.f * x);
  return 1.f - 2.f * rcpf(e + 1.f);
}

// ---- MALL-coherent (sc0 sc1) ops — the only HW-proven cross-WG path ----
__device__ __forceinline__ u16x8 ldg16s(const unsigned short* p) {
  u16x8 r;
  asm volatile("global_load_dwordx4 %0, %1, off sc0 sc1" : "=v"(r) : "v"(p));
  return r;
}
__device__ __forceinline__ void stg16s(unsigned short* p, u16x8 v) {
  asm volatile("global_store_dwordx4 %0, %1, off sc0 sc1" :: "v"(p), "v"(v) : "memory");
}
__device__ __forceinline__ unsigned ld_flag(const unsigned int* p) {
  unsigned v;
  asm volatile("global_load_dword %0, %1, off sc0 sc1" : "=v"(v) : "v"(p) : "memory");
  return v;
}
__device__ __forceinline__ void st_flag(unsigned int* p, unsigned v) {
  asm volatile("global_store_dword %0, %1, off sc0 sc1" :: "v"(p), "v"(v) : "memory");
}
#define VM_WAIT0 do { asm volatile("s_waitcnt vmcnt(0)" ::: "memory"); __builtin_amdgcn_sched_barrier(0); } while (0)

// ---- step tags in fp16 mantissa bit0: tag(s) = ((s+8)>>3)&1 (flips per ring lap) ----
__device__ __forceinline__ bool chunk_fresh(u16x8 v, unsigned tp) {
  u32x4 d = __builtin_bit_cast(u32x4, v);
  return ((d[0] & 0x00010001u) == tp) & ((d[1] & 0x00010001u) == tp) &
         ((d[2] & 0x00010001u) == tp) & ((d[3] & 0x00010001u) == tp);
}
__device__ __forceinline__ u16x8 tag_chunk(u16x8 v, unsigned tp) {
  u32x4 d = __builtin_bit_cast(u32x4, v);
  d &= 0xFFFEFFFEu;
  d |= tp;
  return __builtin_bit_cast(u16x8, d);
}
__device__ __forceinline__ f16x8 cvt8(float4 a, float4 b) {
  f16x8 s;
  s[0]=(_Float16)a.x; s[1]=(_Float16)a.y; s[2]=(_Float16)a.z; s[3]=(_Float16)a.w;
  s[4]=(_Float16)b.x; s[5]=(_Float16)b.y; s[6]=(_Float16)b.z; s[7]=(_Float16)b.w;
  return s;
}

// ---------------- init: scrub rings to tag-0, write t=-1 state (tag 0) ----------------
__global__ void __launch_bounds__(256) init_state(const float* __restrict__ hs, char* __restrict__ ws) {
  int g = blockIdx.x, tid = threadIdx.x;
  char* gb = ws + (size_t)g * GSTRIDE;
  uint4 z4 = {0,0,0,0};
  int total16 = (CNT_OFF + 512) / 16;
  for (int i = tid; i < total16; i += 256) ((uint4*)gb)[i] = z4;   // rings zeroed -> tag 0
  __syncthreads();
  int b0 = g * MR;
  unsigned short* H0 = (unsigned short*)(gb + H0_OFF + 7*(size_t)H0_SLOT);
  unsigned short* H1 = (unsigned short*)(gb + H1_OFF + 7*(size_t)H1_SLOT);
  unsigned short* C2 = (unsigned short*)(gb + C2_OFF);
  for (int i = tid; i < MR*H0P; i += 256) { int r = i/H0P, c = i%H0P;
    H0[i] = (c < H0N) ? (unsigned short)(f2h_bits(hs[(size_t)(b0+r)*512 + c]) & 0xFFFEu) : (unsigned short)0; }
  for (int i = tid; i < MR*H1P; i += 256) { int r = i/H1P, c = i%H1P;
    H1[i] = (c < H1N) ? (unsigned short)(f2h_bits(hs[(size_t)(b0+r)*512 + H0N + c]) & 0xFFFEu) : (unsigned short)0; }
  for (int i = tid; i < MR*64;  i += 256) { int r = i>>6,  c = i&63;
    C2[i] = f2h_bits(hs[(size_t)(b0+r)*512 + 448 + c]); }
}

// ---------------- weight fragment builder, 3 gates (gate2 = W_ta + W_tb) ----------------
template<int KK, int MODE>
__device__ __forceinline__ void build_frag3(f16x8* wf, const float* __restrict__ W, const float* __restrict__ Msk,
                                            int h, int Kreal, int g4, int tile, int lane) {
  int col = tile * 16 + (lane & 15);
  bool nv = (col < h);
  #pragma unroll
  for (int kk = 0; kk < KK; ++kk) {
    f16x8 s;
    #pragma unroll
    for (int e = 0; e < 8; ++e) {
      int k = kk*32 + ((lane >> 4) << 3) + e;
      int wc;
      if (MODE == 0)      wc = (k < 333) ? k : -1;
      else if (MODE == 1) wc = (k < 269) ? k : ((k >= 272 && k < 451) ? (k - 3) : -1);
      else                wc = (k < 179) ? k : ((k >= 192 && k < 256) ? (k - 13) : -1);
      float val = 0.f;
      if (nv && wc >= 0) {
        if (g4 < 2) val = W[(size_t)(g4 * h + col) * Kreal + wc] * Msk[(size_t)col * Kreal + wc];
        else        val = W[(size_t)(2 * h + col) * Kreal + wc] + W[(size_t)(3 * h + col) * Kreal + wc];
      }
      s[e] = (_Float16)val;
    }
    wf[kk] = s;
  }
}

__device__ __forceinline__ f16x8 lda(const unsigned short* xh, int stride, int mt, int kk, int lane) {
  const unsigned short* p = xh + (size_t)(mt*16 + (lane & 15)) * stride + kk*32 + ((lane >> 4) << 3);
  return __builtin_bit_cast(f16x8, *(const u16x8*)p);
}

// ---------------- persistent cascade kernel ----------------
// 16 groups x 9 WGs. j=0..4 cell0 (tile-per-wave, 17 active waves, NO barriers);
// j=5..7 cell1 (12 waves, NO barriers); j=8 cell2+y (WG-wide, barriers, off-chain).
// Sync: data-as-flag (mantissa-bit0 step tags) polled DIRECTLY INTO MFMA A-fragment
// registers — poll success == operand ready, MFMA fires from regs (no LDS staging).
// Guard flags (per-wave): cnt[0..16] cell0 waves, cnt[20..31] cell1 waves,
// cnt[32] cell2 WG; flag=t+1 once that consumer's step-t operand loads completed.
// Ring-overwrite guards: cell0 wave@t (writes slot t&7, kills a_{t-8}) needs
// cnt[0..16]>=t-6 and cnt[20..31]>=t-7; cell1 wave@t needs cnt[20..31]>=t-6,
// cnt[32]>=t-7. Acyclic in t -> deadlock-free; bounded spins.
__global__ void __launch_bounds__(256, 1) rnn_persist(
    const float* __restrict__ dt,
    const float* __restrict__ W0, const float* __restrict__ b0v,
    const float* __restrict__ W1, const float* __restrict__ b1v,
    const float* __restrict__ W2, const float* __restrict__ b2v,
    const float* __restrict__ Wout, const float* __restrict__ boutg,
    const float* __restrict__ M0, const float* __restrict__ M1, const float* __restrict__ M2,
    float* __restrict__ out, char* __restrict__ ws)
{
  __shared__ __attribute__((aligned(16))) unsigned short xhS[MR * XH2S];  // cell2 b-stage
  __shared__ __attribute__((aligned(16))) unsigned short hbuf[4][32][16]; // per-wave (c2: cross-wave)

  int tid = threadIdx.x;
  int lane = tid & 63, wave = tid >> 6;
  int bid = blockIdx.x;
  int j = bid >> 4;
  int g = bid & 15;
  int b0 = g * MR;

  char* gb = ws + (size_t)g * GSTRIDE;
  unsigned short* H0r = (unsigned short*)(gb + H0_OFF);
  unsigned short* H1r = (unsigned short*)(gb + H1_OFF);
  unsigned int*   cnt = (unsigned int*)(gb + CNT_OFF);
  int r0 = lane & 15, ks = (lane >> 4) * 8;
  u16x8 zz = {0,0,0,0,0,0,0,0};

  if (j < 5) {
    // ================= cell0: fragment-direct, barrier-free =================
    int tile = j*4 + wave;
    if (tile >= 17) return;                 // inactive waves exit (no barriers in this path)
    int ncol = tile*16 + r0;
    bool cok = (ncol < H0N);
    f16x8 wf[3][KK0];
    #pragma unroll
    for (int g4 = 0; g4 < 3; ++g4) build_frag3<KK0,0>(wf[g4], W0, M0, H0N, K0REAL, g4, tile, lane);
    float bb[3] = {0.f,0.f,0.f};
    if (cok) {
      bb[0] = b0v[ncol]; bb[1] = b0v[H0N + ncol];
      bb[2] = b0v[2*H0N + ncol] + b0v[3*H0N + ncol];
    }
    // A-fragment h-chunks: kk=2..10, ring col = kk*32+ks-64 (zero when col>=272)
    u16x8 tA[2][9];
    bool hval[9];
    #pragma unroll
    for (int q = 0; q < 9; ++q) {
      hval[q] = ((q + 2)*32 + ks - 64) < 272;
      tA[0][q] = zz; tA[1][q] = zz;
    }
    // x fragments (kk=0,1) prefetched from dt
    const float* xp0 = dt + (size_t)(b0 + r0) * (LSEQ*64);
    const float* xp1 = dt + (size_t)(b0 + r0 + 16) * (LSEQ*64);
    float4 xs[8];
    #pragma unroll
    for (int c = 0; c < 2; ++c) {
      xs[c*2]   = *(const float4*)(xp0 + c*32 + ks);
      xs[c*2+1] = *(const float4*)(xp0 + c*32 + ks + 4);
      xs[4+c*2]   = *(const float4*)(xp1 + c*32 + ks);
      xs[4+c*2+1] = *(const float4*)(xp1 + c*32 + ks + 4);
    }
    int gt_base = (lane < 17) ? -6 : (lane >= 20 && lane < 32) ? -7 : BIGNEG;
    for (int t = 0; t < LSEQ; ++t) {
      unsigned tpm1 = (((unsigned)(t + 7) >> 3) & 1) * 0x00010001u;  // tag a_{t-1}
      unsigned tpt  = (((unsigned)(t + 8) >> 3) & 1) * 0x00010001u;  // tag a_t
      const unsigned short* H0s = H0r + (size_t)((t + 7) & 7) * (MR*H0P);
      const unsigned short* row0 = H0s + (size_t)r0 * H0P;
      const unsigned short* row1 = H0s + (size_t)(r0 + 16) * H0P;
      int gt = t + gt_base;
      for (int it = 0; it < (1 << 17); ++it) {   // poll: fragments ARE the flag
        unsigned gv = 0;
        if (gt_base != BIGNEG) gv = ld_flag(cnt + lane);
        #pragma unroll
        for (int q = 0; q < 9; ++q) {
          if (hval[q]) {
            tA[0][q] = ldg16s(row0 + (q + 2)*32 + ks - 64);
            tA[1][q] = ldg16s(row1 + (q + 2)*32 + ks - 64);
          }
        }
        VM_WAIT0;
        bool ok = ((int)gv >= gt);
        #pragma unroll
        for (int q = 0; q < 9; ++q) if (hval[q]) ok &= chunk_fresh(tA[0][q], tpm1) & chunk_fresh(tA[1][q], tpm1);
        if (__all(ok)) break;
        __builtin_amdgcn_s_sleep(1);
      }
      if (lane == 0) st_flag(&cnt[tile], t + 1);    // my step-t reads done (ring guard)
      // convert x_t fragments (loads covered by poll's vmcnt0)
      f16x8 xf[2][2];
      xf[0][0] = cvt8(xs[0], xs[1]); xf[1][0] = cvt8(xs[2], xs[3]);
      xf[0][1] = cvt8(xs[4], xs[5]); xf[1][1] = cvt8(xs[6], xs[7]);
      { // issue x prefetch for t+1 (in flight under MFMA/combine)
        int tn = (t + 1 < LSEQ) ? t + 1 : t;
        #pragma unroll
        for (int c = 0; c < 2; ++c) {
          xs[c*2]   = *(const float4*)(xp0 + (size_t)tn*64 + c*32 + ks);
          xs[c*2+1] = *(const float4*)(xp0 + (size_t)tn*64 + c*32 + ks + 4);
          xs[4+c*2]   = *(const float4*)(xp1 + (size_t)tn*64 + c*32 + ks);
          xs[4+c*2+1] = *(const float4*)(xp1 + (size_t)tn*64 + c*32 + ks + 4);
        }
      }
      f32x4 ac[3][2];
      #pragma unroll
      for (int g4 = 0; g4 < 3; ++g4) { ac[g4][0] = (f32x4){0,0,0,0}; ac[g4][1] = (f32x4){0,0,0,0}; }
      #pragma unroll
      for (int kk = 0; kk < KK0; ++kk) {
        f16x8 a0 = (kk < 2) ? xf[kk][0] : F16(tA[0][kk-2]);
        f16x8 a1 = (kk < 2) ? xf[kk][1] : F16(tA[1][kk-2]);
        #pragma unroll
        for (int g4 = 0; g4 < 3; ++g4) {
          ac[g4][0] = MFMA16(a0, wf[g4][kk], ac[g4][0]);
          ac[g4][1] = MFMA16(a1, wf[g4][kk], ac[g4][1]);
        }
      }
      #pragma unroll
      for (int m = 0; m < 2; ++m) {
        #pragma unroll
        for (int r = 0; r < 4; ++r) {
          float ti = fast_sig(ac[2][m][r] + bb[2]);
          float hv = cok ? (fast_tanh(ac[0][m][r] + bb[0])*(1.f - ti) + ti*fast_tanh(ac[1][m][r] + bb[1])) : 0.f;
          hbuf[wave][m*16 + (lane>>4)*4 + r][r0] = f2h_bits(hv);
        }
      }
      int srow = lane >> 1, c8v = (lane & 1) * 8;
      u16x8 hv8 = tag_chunk(*(const u16x8*)&hbuf[wave][srow][c8v], tpt);
      unsigned short* Hn = H0r + (size_t)(t & 7) * (MR*H0P);
      stg16s(Hn + (size_t)srow*H0P + tile*16 + c8v, hv8);   // tagged store IS the flag
    }
  } else if (j < 8) {
    // ================= cell1: fragment-direct, barrier-free =================
    int tile = (j - 5)*4 + wave;
    int ncol = tile*16 + r0;
    bool cok = (ncol < H1N);
    f16x8 wf[3][KK1];
    #pragma unroll
    for (int g4 = 0; g4 < 3; ++g4) build_frag3<KK1,1>(wf[g4], W1, M1, H1N, K1REAL, g4, tile, lane);
    float bb[3] = {0.f,0.f,0.f};
    if (cok) {
      bb[0] = b1v[ncol]; bb[1] = b1v[H1N + ncol];
      bb[2] = b1v[2*H1N + ncol] + b1v[3*H1N + ncol];
    }
    // chunks kk=0..14: k=kk*32+ks; a-ring if k<272 else b-ring col k-272 (zero if k>=464)
    u16x8 tS[2][KK1];
    bool isa[KK1], val[KK1];
    int coff[KK1];
    #pragma unroll
    for (int kk = 0; kk < KK1; ++kk) {
      int k = kk*32 + ks;
      isa[kk] = (k < 272);
      val[kk] = (k < 464);
      coff[kk] = isa[kk] ? k : (k - 272);
      tS[0][kk] = zz; tS[1][kk] = zz;
    }
    int gt_base = (lane >= 20 && lane < 32) ? -6 : (lane == 32) ? -7 : BIGNEG;
    for (int t = 0; t < LSEQ; ++t) {
      unsigned tpm1 = (((unsigned)(t + 7) >> 3) & 1) * 0x00010001u;  // b_{t-1}
      unsigned tpt  = (((unsigned)(t + 8) >> 3) & 1) * 0x00010001u;  // a_t / b_t
      const unsigned short* As = H0r + (size_t)(t & 7) * (MR*H0P);
      const unsigned short* Bs = H1r + (size_t)((t + 7) & 7) * (MR*H1P);
      const unsigned short* ar0 = As + (size_t)r0 * H0P;
      const unsigned short* ar1 = As + (size_t)(r0 + 16) * H0P;
      const unsigned short* br0 = Bs + (size_t)r0 * H1P;
      const unsigned short* br1 = Bs + (size_t)(r0 + 16) * H1P;
      int gt = t + gt_base;
      for (int it = 0; it < (1 << 17); ++it) {
        unsigned gv = 0;
        if (gt_base != BIGNEG) gv = ld_flag(cnt + lane);
        #pragma unroll
        for (int kk = 0; kk < KK1; ++kk) {
          if (val[kk]) {
            tS[0][kk] = ldg16s((isa[kk] ? ar0 : br0) + coff[kk]);
            tS[1][kk] = ldg16s((isa[kk] ? ar1 : br1) + coff[kk]);
          }
        }
        VM_WAIT0;
        bool ok = ((int)gv >= gt);
        #pragma unroll
        for (int kk = 0; kk < KK1; ++kk) {
          if (val[kk]) {
            unsigned tp = isa[kk] ? tpt : tpm1;
            ok &= chunk_fresh(tS[0][kk], tp) & chunk_fresh(tS[1][kk], tp);
          }
        }
        if (__all(ok)) break;
        __builtin_amdgcn_s_sleep(1);
      }
      if (lane == 0) st_flag(&cnt[20 + tile], t + 1);
      f32x4 ac[3][2];
      #pragma unroll
      for (int g4 = 0; g4 < 3; ++g4) { ac[g4][0] = (f32x4){0,0,0,0}; ac[g4][1] = (f32x4){0,0,0,0}; }
      #pragma unroll
      for (int kk = 0; kk < KK1; ++kk) {
        f16x8 a0 = F16(tS[0][kk]);
        f16x8 a1 = F16(tS[1][kk]);
        #pragma unroll
        for (int g4 = 0; g4 < 3; ++g4) {
          ac[g4][0] = MFMA16(a0, wf[g4][kk], ac[g4][0]);
          ac[g4][1] = MFMA16(a1, wf[g4][kk], ac[g4][1]);
        }
      }
      #pragma unroll
      for (int m = 0; m < 2; ++m) {
        #pragma unroll
        for (int r = 0; r < 4; ++r) {
          float ti = fast_sig(ac[2][m][r] + bb[2]);
          float hv = cok ? (fast_tanh(ac[0][m][r] + bb[0])*(1.f - ti) + ti*fast_tanh(ac[1][m][r] + bb[1])) : 0.f;
          hbuf[wave][m*16 + (lane>>4)*4 + r][r0] = f2h_bits(hv);
        }
      }
      int srow = lane >> 1, c8v = (lane & 1) * 8;
      u16x8 hv8 = tag_chunk(*(const u16x8*)&hbuf[wave][srow][c8v], tpt);
      unsigned short* Hn = H1r + (size_t)(t & 7) * (MR*H1P);
      stg16s(Hn + (size_t)srow*H1P + tile*16 + c8v, hv8);
    }
  } else {
    // ================= cell2 + y (round-9 structure: WG-staged, barriers) =================
    int tile = wave;
    int ncol = tile*16 + r0;
    f16x8 wf[3][KK2], woutf[2];
    #pragma unroll
    for (int g4 = 0; g4 < 3; ++g4) build_frag3<KK2,2>(wf[g4], W2, M2, 64, K2REAL, g4, tile, lane);
    {
      #pragma unroll
      for (int kk = 0; kk < 2; ++kk) {
        f16x8 s;
        #pragma unroll
        for (int e = 0; e < 8; ++e) {
          int k = kk*32 + ks + e;
          s[e] = (_Float16)Wout[(size_t)ncol*64 + k];
        }
        woutf[kk] = s;
      }
    }
    float bov = boutg[ncol];
    float bb[3];
    bb[0] = b2v[ncol]; bb[1] = b2v[64 + ncol];
    bb[2] = b2v[2*64 + ncol] + b2v[3*64 + ncol];
    { // preload c_{-1}
      const unsigned short* C2i = (const unsigned short*)(gb + C2_OFF);
      int r = tid >> 3, c8 = (tid & 7) * 8;
      u16x8 cv = ldg16s(C2i + r*64 + c8);
      VM_WAIT0;
      *(u16x8*)&hbuf[c8 >> 4][r][c8 & 15] = cv;
    }
    int soff[NQ2], sdst[NQ2];
    #pragma unroll
    for (int q = 0; q < NQ2; ++q) {
      int idx = tid + q*256;
      int r = idx / 24, cc = (idx % 24) * 8;
      soff[q] = r*H1P + cc; sdst[q] = r*XH2S + cc;
    }
    for (int t = 0; t < LSEQ; ++t) {
      unsigned tpt = (((unsigned)(t + 8) >> 3) & 1) * 0x00010001u;  // b_t
      const unsigned short* Bs = H1r + (size_t)(t & 7) * (MR*H1P);
      u16x8 tS[NQ2];
      for (int it = 0; it < (1 << 17); ++it) {
        #pragma unroll
        for (int q = 0; q < NQ2; ++q) tS[q] = ldg16s(Bs + soff[q]);
        VM_WAIT0;
        bool ok = true;
        #pragma unroll
        for (int q = 0; q < NQ2; ++q) ok &= chunk_fresh(tS[q], tpt);
        if (__all(ok)) break;
        __builtin_amdgcn_s_sleep(1);
      }
      #pragma unroll
      for (int q = 0; q < NQ2; ++q) *(u16x8*)(xhS + sdst[q]) = tS[q];
      __syncthreads();                       // barA
      if (tid == 0) st_flag(&cnt[32], t + 1); // b_t consumed -> release b-ring slot
      f32x4 ac[3][2];
      #pragma unroll
      for (int g4 = 0; g4 < 3; ++g4) { ac[g4][0] = (f32x4){0,0,0,0}; ac[g4][1] = (f32x4){0,0,0,0}; }
      #pragma unroll
      for (int kk = 0; kk < KK2; ++kk) {
        f16x8 a0, a1;
        if (kk < 6) {
          a0 = lda(xhS, XH2S, 0, kk, lane);
          a1 = lda(xhS, XH2S, 1, kk, lane);
        } else {  // c_{t-1} from hbuf
          int k0 = kk*32 + ks - 192;
          a0 = __builtin_bit_cast(f16x8, *(const u16x8*)&hbuf[k0 >> 4][r0][k0 & 15]);
          a1 = __builtin_bit_cast(f16x8, *(const u16x8*)&hbuf[k0 >> 4][16 + r0][k0 & 15]);
        }
        #pragma unroll
        for (int g4 = 0; g4 < 3; ++g4) {
          ac[g4][0] = MFMA16(a0, wf[g4][kk], ac[g4][0]);
          ac[g4][1] = MFMA16(a1, wf[g4][kk], ac[g4][1]);
        }
      }
      __syncthreads();                       // barB (hbuf c_{t-1} reads done)
      {
        #pragma unroll
        for (int m = 0; m < 2; ++m) {
          #pragma unroll
          for (int r = 0; r < 4; ++r) {
            float ti = fast_sig(ac[2][m][r] + bb[2]);
            float hv = fast_tanh(ac[0][m][r] + bb[0])*(1.f - ti) + ti*fast_tanh(ac[1][m][r] + bb[1]);
            hbuf[wave][m*16 + (lane>>4)*4 + r][r0] = f2h_bits(hv);
          }
        }
      }
      __syncthreads();                       // barC (c_t complete in hbuf)
      { // y_t = c_t @ Wout^T + bout
        #pragma unroll
        for (int m = 0; m < 2; ++m) {
          f32x4 acc = {0.f,0.f,0.f,0.f};
          #pragma unroll
          for (int kk = 0; kk < 2; ++kk) {
            int k0 = kk*32 + ks;
            f16x8 a = __builtin_bit_cast(f16x8, *(const u16x8*)&hbuf[k0 >> 4][m*16 + r0][k0 & 15]);
            acc = MFMA16(a, woutf[kk], acc);
          }
          int rb = (lane >> 4) * 4;
          #pragma unroll
          for (int r = 0; r < 4; ++r) {
            int row = m*16 + rb + r;
            out[((size_t)(b0 + row) * LSEQ + t) * 64 + tile*16 + r0] = acc[r] + bov;
          }
        }
      }
    }
  }
}

extern "C" void kernel_launch(void* const* d_in, const int* in_sizes, int n_in,
                              void* d_out, int out_size, void* d_ws, size_t ws_size,
                              hipStream_t stream) {
  const float* dt   = (const float*)d_in[0];
  const float* hs   = (const float*)d_in[1];
  const float* W0   = (const float*)d_in[2];
  const float* b0v  = (const float*)d_in[3];
  const float* W1   = (const float*)d_in[4];
  const float* b1v  = (const float*)d_in[5];
  const float* W2   = (const float*)d_in[6];
  const float* b2v  = (const float*)d_in[7];
  const float* Wo   = (const float*)d_in[8];
  const float* bo   = (const float*)d_in[9];
  const float* M0   = (const float*)d_in[10];
  const float* M1   = (const float*)d_in[11];
  const float* M2   = (const float*)d_in[12];
  (void)in_sizes; (void)n_in; (void)out_size; (void)ws_size;
  init_state<<<16, 256, 0, stream>>>(hs, (char*)d_ws);
  rnn_persist<<<144, 256, 0, stream>>>(dt, W0, b0v, W1, b1v, W2, b2v, Wo, bo, M0, M1, M2,
                                       (float*)d_out, (char*)d_ws);
}

// Round 12
// 1922.010 us; speedup vs baseline: 1.3195x; 1.3195x over previous
//
#include <hip/hip_runtime.h>
#include <stdint.h>

typedef _Float16 f16x8 __attribute__((ext_vector_type(8)));
typedef unsigned short u16x8 __attribute__((ext_vector_type(8)));
typedef float f32x4 __attribute__((ext_vector_type(4)));
typedef unsigned int u32x4 __attribute__((ext_vector_type(4)));

#define MFMA16(a,b,c) __builtin_amdgcn_mfma_f32_16x16x32_f16((a),(b),(c),0,0,0)
#define F16(v) __builtin_bit_cast(f16x8, (v))

// problem dims
#define LSEQ 256
#define H0N  269
#define H1N  179
#define H0P  272
#define H1P  192
#define K0REAL 333
#define K1REAL 448
#define K2REAL 243
#define KK0  11    // cell0 K padded to 352 ([x64|h:272pad] + 16 zero)
#define KK1  15    // cell1 K padded to 480 ([a:272|b:192pad] + 16 zero)
#define KK2  8     // cell2 [b:192|c:64(hbuf)]
#define XH0S 360
#define XH1S 488
#define XH2S 200
#define MR   64    // batch rows per group (8 groups)

// ws layout per group (bytes)
#define H0_OFF   0
#define H0_SLOT  (MR*H0P*2)            // 34816
#define H1_OFF   (8*H0_SLOT)           // 278528
#define H1_SLOT  (MR*H1P*2)            // 24576
#define C2_OFF   (H1_OFF + 8*H1_SLOT)  // 475136 (c_{-1} init slot, 8KB)
#define CNT_OFF  (C2_OFF + MR*64*2)    // 483328 (9 per-WG guard flags)
#define GSTRIDE  524288                // 512 KiB x 8 groups = 4 MB

#define BIGNEG   (-(1<<28))
#define NQ0 9    // ceil(64*34/256)
#define NQ1 15   // ceil((64*34+64*24)/256)
#define NQ2 6    // 64*24/256

__device__ __forceinline__ unsigned short f2h_bits(float v) {
  return __builtin_bit_cast(unsigned short, (_Float16)v);
}
__device__ __forceinline__ float rcpf(float x) { return __builtin_amdgcn_rcpf(x); }
__device__ __forceinline__ float fast_sig(float s) { return rcpf(1.f + __expf(-s)); }
__device__ __forceinline__ float fast_tanh(float x) {
  float e = __expf(2.f * x);
  return 1.f - 2.f * rcpf(e + 1.f);
}

// ---- MALL-coherent (sc0 sc1) ops — the only HW-proven cross-WG path ----
__device__ __forceinline__ u16x8 ldg16s(const unsigned short* p) {
  u16x8 r;
  asm volatile("global_load_dwordx4 %0, %1, off sc0 sc1" : "=v"(r) : "v"(p));
  return r;
}
__device__ __forceinline__ void stg16s(unsigned short* p, u16x8 v) {
  asm volatile("global_store_dwordx4 %0, %1, off sc0 sc1" :: "v"(p), "v"(v) : "memory");
}
__device__ __forceinline__ unsigned ld_flag(const unsigned int* p) {
  unsigned v;
  asm volatile("global_load_dword %0, %1, off sc0 sc1" : "=v"(v) : "v"(p) : "memory");
  return v;
}
__device__ __forceinline__ void st_flag(unsigned int* p, unsigned v) {
  asm volatile("global_store_dword %0, %1, off sc0 sc1" :: "v"(p), "v"(v) : "memory");
}
#define VM_WAIT0 do { asm volatile("s_waitcnt vmcnt(0)" ::: "memory"); __builtin_amdgcn_sched_barrier(0); } while (0)

// ---- step tags in fp16 mantissa bit0: tag(s) = ((s+8)>>3)&1 (flips per ring lap) ----
__device__ __forceinline__ bool chunk_fresh(u16x8 v, unsigned tp) {
  u32x4 d = __builtin_bit_cast(u32x4, v);
  return ((d[0] & 0x00010001u) == tp) & ((d[1] & 0x00010001u) == tp) &
         ((d[2] & 0x00010001u) == tp) & ((d[3] & 0x00010001u) == tp);
}
__device__ __forceinline__ u16x8 tag_chunk(u16x8 v, unsigned tp) {
  u32x4 d = __builtin_bit_cast(u32x4, v);
  d &= 0xFFFEFFFEu;
  d |= tp;
  return __builtin_bit_cast(u16x8, d);
}

// ---------------- init: scrub rings to tag-0, write t=-1 state (tag 0) ----------------
__global__ void __launch_bounds__(256) init_state(const float* __restrict__ hs, char* __restrict__ ws) {
  int g = blockIdx.x, tid = threadIdx.x;
  char* gb = ws + (size_t)g * GSTRIDE;
  uint4 z4 = {0,0,0,0};
  int total16 = (CNT_OFF + 512) / 16;
  for (int i = tid; i < total16; i += 256) ((uint4*)gb)[i] = z4;   // rings zeroed -> tag 0
  __syncthreads();
  int b0 = g * MR;
  unsigned short* H0 = (unsigned short*)(gb + H0_OFF + 7*(size_t)H0_SLOT);
  unsigned short* H1 = (unsigned short*)(gb + H1_OFF + 7*(size_t)H1_SLOT);
  unsigned short* C2 = (unsigned short*)(gb + C2_OFF);
  for (int i = tid; i < MR*H0P; i += 256) { int r = i/H0P, c = i%H0P;
    H0[i] = (c < H0N) ? (unsigned short)(f2h_bits(hs[(size_t)(b0+r)*512 + c]) & 0xFFFEu) : (unsigned short)0; }
  for (int i = tid; i < MR*H1P; i += 256) { int r = i/H1P, c = i%H1P;
    H1[i] = (c < H1N) ? (unsigned short)(f2h_bits(hs[(size_t)(b0+r)*512 + H0N + c]) & 0xFFFEu) : (unsigned short)0; }
  for (int i = tid; i < MR*64;  i += 256) { int r = i>>6,  c = i&63;
    C2[i] = f2h_bits(hs[(size_t)(b0+r)*512 + 448 + c]); }
}

// ---------------- weight fragment builder, 3 gates (gate2 = W_ta + W_tb) ----------------
template<int KK, int MODE>
__device__ __forceinline__ void build_frag3(f16x8* wf, const float* __restrict__ W, const float* __restrict__ Msk,
                                            int h, int Kreal, int g4, int tile, int lane) {
  int col = tile * 16 + (lane & 15);
  bool nv = (col < h);
  #pragma unroll
  for (int kk = 0; kk < KK; ++kk) {
    f16x8 s;
    #pragma unroll
    for (int e = 0; e < 8; ++e) {
      int k = kk*32 + ((lane >> 4) << 3) + e;
      int wc;
      if (MODE == 0)      wc = (k < 333) ? k : -1;
      else if (MODE == 1) wc = (k < 269) ? k : ((k >= 272 && k < 451) ? (k - 3) : -1);
      else                wc = (k < 179) ? k : ((k >= 192 && k < 256) ? (k - 13) : -1);
      float val = 0.f;
      if (nv && wc >= 0) {
        if (g4 < 2) val = W[(size_t)(g4 * h + col) * Kreal + wc] * Msk[(size_t)col * Kreal + wc];
        else        val = W[(size_t)(2 * h + col) * Kreal + wc] + W[(size_t)(3 * h + col) * Kreal + wc];
      }
      s[e] = (_Float16)val;
    }
    wf[kk] = s;
  }
}

__device__ __forceinline__ f16x8 lda(const unsigned short* xh, int stride, int mt, int kk, int lane) {
  const unsigned short* p = xh + (size_t)(mt*16 + (lane & 15)) * stride + kk*32 + ((lane >> 4) << 3);
  return __builtin_bit_cast(f16x8, *(const u16x8*)p);
}

// ---------------- persistent cascade kernel (r9 protocol, M=64 / 8 groups) ----------------
// 8 groups x 9 WGs. j=0..4 cell0 (tile=j*4+wave, 17 active waves); j=5..7 cell1
// (12 waves); j=8 cell2+y. WG-coalesced staging; data-as-flag (mantissa-bit0
// step tags). Per-WG guard flags cnt[0..8] (cnt[j]=t+1 after WG j finished
// STAGING step t). Ring-overwrite guards: cell0@t needs cnt[0..4]>=t-6,
// cnt[5..7]>=t-7; cell1@t needs cnt[5..7]>=t-6, cnt[8]>=t-7. Acyclic in t.
__global__ void __launch_bounds__(256, 1) rnn_persist(
    const float* __restrict__ dt,
    const float* __restrict__ W0, const float* __restrict__ b0v,
    const float* __restrict__ W1, const float* __restrict__ b1v,
    const float* __restrict__ W2, const float* __restrict__ b2v,
    const float* __restrict__ Wout, const float* __restrict__ boutg,
    const float* __restrict__ M0, const float* __restrict__ M1, const float* __restrict__ M2,
    float* __restrict__ out, char* __restrict__ ws)
{
  __shared__ __attribute__((aligned(16))) unsigned short xhS[MR * XH1S];  // 62464 B
  __shared__ __attribute__((aligned(16))) unsigned short hbuf[4][MR][16]; // 8 KB

  int tid = threadIdx.x;
  int lane = tid & 63, wave = tid >> 6;
  int bid = blockIdx.x;
  int j = bid >> 3;          // role 0..8
  int g = bid & 7;           // group 0..7 (bid%8 ~ XCD heuristic)
  int b0 = g * MR;

  char* gb = ws + (size_t)g * GSTRIDE;
  unsigned short* H0r = (unsigned short*)(gb + H0_OFF);
  unsigned short* H1r = (unsigned short*)(gb + H1_OFF);
  unsigned int*   cnt = (unsigned int*)(gb + CNT_OFF);
  int r0 = lane & 15;
  u16x8 zz = {0,0,0,0,0,0,0,0};

  if (j < 5) {
    // ================= cell0 =================
    int tile = j*4 + wave;
    bool act = (tile < 17);
    int ncol = tile*16 + r0;
    bool cok = act && (ncol < H0N);
    f16x8 wf[3][KK0];
    if (act) {
      #pragma unroll
      for (int g4 = 0; g4 < 3; ++g4) build_frag3<KK0,0>(wf[g4], W0, M0, H0N, K0REAL, g4, tile, lane);
    }
    float bb[3] = {0.f,0.f,0.f};
    if (cok) {
      bb[0] = b0v[ncol]; bb[1] = b0v[H0N + ncol];
      bb[2] = b0v[2*H0N + ncol] + b0v[3*H0N + ncol];
    }
    if (tid < 128) {  // static k-pad cols 336..351 (64 rows x 2 chunks)
      int r = tid >> 1, c8 = 336 + (tid & 1)*8;
      *(u16x8*)(xhS + (size_t)r*XH0S + c8) = zz;
    }
    int aoff[NQ0], adst[NQ0]; bool aval[NQ0];
    #pragma unroll
    for (int q = 0; q < NQ0; ++q) {
      int idx = tid + q*256;
      aval[q] = (idx < MR*34);
      int r = idx / 34, cc = (idx % 34) * 8;
      aoff[q] = r*H0P + cc;
      adst[q] = r*XH0S + 64 + cc;
    }
    // x staging: thread covers rows (tid>>3) and (tid>>3)+32, cols (tid&7)*8
    int xrow = tid >> 3, xc = (tid & 7) * 8;
    const float* dtb0 = dt + ((size_t)(b0 + xrow) * LSEQ) * 64 + xc;
    const float* dtb1 = dtb0 + (size_t)32 * LSEQ * 64;
    float4 xA0 = *(const float4*)(dtb0), xB0 = *(const float4*)(dtb0 + 4);
    float4 xA1 = *(const float4*)(dtb1), xB1 = *(const float4*)(dtb1 + 4);
    int goff = (lane < 5) ? -6 : (lane < 8) ? -7 : BIGNEG;
    for (int t = 0; t < LSEQ; ++t) {
      unsigned tpm1 = (((unsigned)(t + 7) >> 3) & 1) * 0x00010001u;  // tag a_{t-1}
      unsigned tpt  = (((unsigned)(t + 8) >> 3) & 1) * 0x00010001u;  // tag a_t
      { // write x_t from prefetched regs
        unsigned short* d0 = xhS + (size_t)xrow*XH0S + xc;
        unsigned short* d1 = xhS + (size_t)(xrow + 32)*XH0S + xc;
        d0[0]=f2h_bits(xA0.x); d0[1]=f2h_bits(xA0.y); d0[2]=f2h_bits(xA0.z); d0[3]=f2h_bits(xA0.w);
        d0[4]=f2h_bits(xB0.x); d0[5]=f2h_bits(xB0.y); d0[6]=f2h_bits(xB0.z); d0[7]=f2h_bits(xB0.w);
        d1[0]=f2h_bits(xA1.x); d1[1]=f2h_bits(xA1.y); d1[2]=f2h_bits(xA1.z); d1[3]=f2h_bits(xA1.w);
        d1[4]=f2h_bits(xB1.x); d1[5]=f2h_bits(xB1.y); d1[6]=f2h_bits(xB1.z); d1[7]=f2h_bits(xB1.w);
      }
      // tag-poll a_{t-1} (WG-coalesced; the poll IS the read) + ring guards
      const unsigned short* H0s = H0r + (size_t)((t + 7) & 7) * (MR*H0P);
      u16x8 tA[NQ0];
      for (int it = 0; it < (1 << 17); ++it) {
        unsigned gv = 0;
        if (lane < 8) gv = ld_flag(cnt + lane);
        #pragma unroll
        for (int q = 0; q < NQ0; ++q) if (aval[q]) tA[q] = ldg16s(H0s + aoff[q]);
        VM_WAIT0;
        bool ok = ((int)gv >= t + goff);
        #pragma unroll
        for (int q = 0; q < NQ0; ++q) if (aval[q]) ok &= chunk_fresh(tA[q], tpm1);
        if (__all(ok)) break;
        __builtin_amdgcn_s_sleep(1);
      }
      #pragma unroll
      for (int q = 0; q < NQ0; ++q) if (aval[q]) *(u16x8*)(xhS + adst[q]) = tA[q];
      __syncthreads();                       // barA
      if (tid == 0) st_flag(&cnt[j], t + 1); // staging done -> release a-ring slot
      { int tn = (t + 1 < LSEQ) ? t + 1 : t; // prefetch x(t+1) under MFMA
        xA0 = *(const float4*)(dtb0 + (size_t)tn*64);
        xB0 = *(const float4*)(dtb0 + (size_t)tn*64 + 4);
        xA1 = *(const float4*)(dtb1 + (size_t)tn*64);
        xB1 = *(const float4*)(dtb1 + (size_t)tn*64 + 4); }
      f32x4 ac[3][4];
      if (act) {
        #pragma unroll
        for (int g4 = 0; g4 < 3; ++g4) {
          #pragma unroll
          for (int m = 0; m < 4; ++m) ac[g4][m] = (f32x4){0,0,0,0};
        }
        #pragma unroll
        for (int kk = 0; kk < KK0; ++kk) {
          #pragma unroll
          for (int m = 0; m < 4; ++m) {
            f16x8 a = lda(xhS, XH0S, m, kk, lane);
            #pragma unroll
            for (int g4 = 0; g4 < 3; ++g4) ac[g4][m] = MFMA16(a, wf[g4][kk], ac[g4][m]);
          }
        }
      }
      __syncthreads();                       // barB (xhS reads done)
      if (act) {
        #pragma unroll
        for (int m = 0; m < 4; ++m) {
          #pragma unroll
          for (int r = 0; r < 4; ++r) {
            float ti = fast_sig(ac[2][m][r] + bb[2]);
            float hv = cok ? (fast_tanh(ac[0][m][r] + bb[0])*(1.f - ti) + ti*fast_tanh(ac[1][m][r] + bb[1])) : 0.f;
            hbuf[wave][m*16 + (lane>>4)*4 + r][r0] = f2h_bits(hv);
          }
        }
        unsigned short* Hn = H0r + (size_t)(t & 7) * (MR*H0P);
        int c8v = (lane & 1) * 8;
        #pragma unroll
        for (int s = 0; s < 2; ++s) {
          int srow = s*32 + (lane >> 1);
          u16x8 hv8 = tag_chunk(*(const u16x8*)&hbuf[wave][srow][c8v], tpt);
          stg16s(Hn + (size_t)srow*H0P + tile*16 + c8v, hv8);   // tagged store IS the flag
        }
      }
    }
  } else if (j < 8) {
    // ================= cell1 =================
    int tile = (j - 5)*4 + wave;
    int ncol = tile*16 + r0;
    bool cok = (ncol < H1N);
    f16x8 wf[3][KK1];
    #pragma unroll
    for (int g4 = 0; g4 < 3; ++g4) build_frag3<KK1,1>(wf[g4], W1, M1, H1N, K1REAL, g4, tile, lane);
    float bb[3] = {0.f,0.f,0.f};
    if (cok) {
      bb[0] = b1v[ncol]; bb[1] = b1v[H1N + ncol];
      bb[2] = b1v[2*H1N + ncol] + b1v[3*H1N + ncol];
    }
    if (tid < 128) {  // static k-pad cols 464..479
      int r = tid >> 1, c8 = 464 + (tid & 1)*8;
      *(u16x8*)(xhS + (size_t)r*XH1S + c8) = zz;
    }
    int soff[NQ1], sdst[NQ1]; bool sval[NQ1], sisB[NQ1];
    #pragma unroll
    for (int q = 0; q < NQ1; ++q) {
      int idx = tid + q*256;
      if (idx < MR*34) {
        sval[q] = true; sisB[q] = false;
        int r = idx / 34, cc = (idx % 34) * 8;
        soff[q] = r*H0P + cc; sdst[q] = r*XH1S + cc;
      } else {
        int i2 = idx - MR*34;
        sval[q] = (i2 < MR*24); sisB[q] = true;
        int r = i2 / 24, cc = (i2 % 24) * 8;
        soff[q] = r*H1P + cc; sdst[q] = r*XH1S + 272 + cc;
      }
    }
    int goff = (lane >= 5 && lane < 8) ? -6 : (lane == 8) ? -7 : BIGNEG;
    for (int t = 0; t < LSEQ; ++t) {
      unsigned tpm1 = (((unsigned)(t + 7) >> 3) & 1) * 0x00010001u;  // b_{t-1}
      unsigned tpt  = (((unsigned)(t + 8) >> 3) & 1) * 0x00010001u;  // a_t / b_t
      const unsigned short* As = H0r + (size_t)(t & 7) * (MR*H0P);
      const unsigned short* Bs = H1r + (size_t)((t + 7) & 7) * (MR*H1P);
      u16x8 tS[NQ1];
      for (int it = 0; it < (1 << 17); ++it) {
        unsigned gv = 0;
        if (lane >= 5 && lane < 9) gv = ld_flag(cnt + lane);
        #pragma unroll
        for (int q = 0; q < NQ1; ++q) if (sval[q]) tS[q] = ldg16s((sisB[q] ? Bs : As) + soff[q]);
        VM_WAIT0;
        bool ok = ((int)gv >= t + goff);
        #pragma unroll
        for (int q = 0; q < NQ1; ++q) {
          if (sval[q]) ok &= chunk_fresh(tS[q], sisB[q] ? tpm1 : tpt);
        }
        if (__all(ok)) break;
        __builtin_amdgcn_s_sleep(1);
      }
      #pragma unroll
      for (int q = 0; q < NQ1; ++q) if (sval[q]) *(u16x8*)(xhS + sdst[q]) = tS[q];
      __syncthreads();                       // barA
      if (tid == 0) st_flag(&cnt[j], t + 1);
      f32x4 ac[3][4];
      #pragma unroll
      for (int g4 = 0; g4 < 3; ++g4) {
        #pragma unroll
        for (int m = 0; m < 4; ++m) ac[g4][m] = (f32x4){0,0,0,0};
      }
      #pragma unroll
      for (int kk = 0; kk < KK1; ++kk) {
        #pragma unroll
        for (int m = 0; m < 4; ++m) {
          f16x8 a = lda(xhS, XH1S, m, kk, lane);
          #pragma unroll
          for (int g4 = 0; g4 < 3; ++g4) ac[g4][m] = MFMA16(a, wf[g4][kk], ac[g4][m]);
        }
      }
      __syncthreads();                       // barB
      {
        #pragma unroll
        for (int m = 0; m < 4; ++m) {
          #pragma unroll
          for (int r = 0; r < 4; ++r) {
            float ti = fast_sig(ac[2][m][r] + bb[2]);
            float hv = cok ? (fast_tanh(ac[0][m][r] + bb[0])*(1.f - ti) + ti*fast_tanh(ac[1][m][r] + bb[1])) : 0.f;
            hbuf[wave][m*16 + (lane>>4)*4 + r][r0] = f2h_bits(hv);
          }
        }
        unsigned short* Hn = H1r + (size_t)(t & 7) * (MR*H1P);
        int c8v = (lane & 1) * 8;
        #pragma unroll
        for (int s = 0; s < 2; ++s) {
          int srow = s*32 + (lane >> 1);
          u16x8 hv8 = tag_chunk(*(const u16x8*)&hbuf[wave][srow][c8v], tpt);
          stg16s(Hn + (size_t)srow*H1P + tile*16 + c8v, hv8);
        }
      }
    }
  } else {
    // ================= cell2 + y (c-state in hbuf; intra-WG) =================
    int tile = wave;
    int ncol = tile*16 + r0;
    int ks = (lane >> 4) * 8;
    f16x8 wf[3][KK2], woutf[2];
    #pragma unroll
    for (int g4 = 0; g4 < 3; ++g4) build_frag3<KK2,2>(wf[g4], W2, M2, 64, K2REAL, g4, tile, lane);
    {
      #pragma unroll
      for (int kk = 0; kk < 2; ++kk) {
        f16x8 s;
        #pragma unroll
        for (int e = 0; e < 8; ++e) {
          int k = kk*32 + ks + e;
          s[e] = (_Float16)Wout[(size_t)ncol*64 + k];
        }
        woutf[kk] = s;
      }
    }
    float bov = boutg[ncol];
    float bb[3];
    bb[0] = b2v[ncol]; bb[1] = b2v[64 + ncol];
    bb[2] = b2v[2*64 + ncol] + b2v[3*64 + ncol];
    { // preload c_{-1} into hbuf (64 rows x 64 cols; 2 chunks/thread)
      const unsigned short* C2i = (const unsigned short*)(gb + C2_OFF);
      #pragma unroll
      for (int q = 0; q < 2; ++q) {
        int idx = tid + q*256;
        int r = idx >> 3, c8 = (idx & 7) * 8;
        u16x8 cv = ldg16s(C2i + r*64 + c8);
        VM_WAIT0;
        *(u16x8*)&hbuf[c8 >> 4][r][c8 & 15] = cv;
      }
    }
    int soff[NQ2], sdst[NQ2];
    #pragma unroll
    for (int q = 0; q < NQ2; ++q) {
      int idx = tid + q*256;
      int r = idx / 24, cc = (idx % 24) * 8;
      soff[q] = r*H1P + cc; sdst[q] = r*XH2S + cc;
    }
    for (int t = 0; t < LSEQ; ++t) {
      unsigned tpt = (((unsigned)(t + 8) >> 3) & 1) * 0x00010001u;  // b_t
      const unsigned short* Bs = H1r + (size_t)(t & 7) * (MR*H1P);
      u16x8 tS[NQ2];
      for (int it = 0; it < (1 << 17); ++it) {
        #pragma unroll
        for (int q = 0; q < NQ2; ++q) tS[q] = ldg16s(Bs + soff[q]);
        VM_WAIT0;
        bool ok = true;
        #pragma unroll
        for (int q = 0; q < NQ2; ++q) ok &= chunk_fresh(tS[q], tpt);
        if (__all(ok)) break;
        __builtin_amdgcn_s_sleep(1);
      }
      #pragma unroll
      for (int q = 0; q < NQ2; ++q) *(u16x8*)(xhS + sdst[q]) = tS[q];
      __syncthreads();                       // barA
      if (tid == 0) st_flag(&cnt[8], t + 1); // b_t consumed -> release b-ring slot
      f32x4 ac[3][4];
      #pragma unroll
      for (int g4 = 0; g4 < 3; ++g4) {
        #pragma unroll
        for (int m = 0; m < 4; ++m) ac[g4][m] = (f32x4){0,0,0,0};
      }
      #pragma unroll
      for (int kk = 0; kk < KK2; ++kk) {
        #pragma unroll
        for (int m = 0; m < 4; ++m) {
          f16x8 a;
          if (kk < 6) {
            a = lda(xhS, XH2S, m, kk, lane);
          } else {  // c_{t-1} from hbuf
            int k0 = kk*32 + ks - 192;
            a = __builtin_bit_cast(f16x8, *(const u16x8*)&hbuf[k0 >> 4][m*16 + r0][k0 & 15]);
          }
          #pragma unroll
          for (int g4 = 0; g4 < 3; ++g4) ac[g4][m] = MFMA16(a, wf[g4][kk], ac[g4][m]);
        }
      }
      __syncthreads();                       // barB (hbuf c_{t-1} reads done)
      {
        #pragma unroll
        for (int m = 0; m < 4; ++m) {
          #pragma unroll
          for (int r = 0; r < 4; ++r) {
            float ti = fast_sig(ac[2][m][r] + bb[2]);
            float hv = fast_tanh(ac[0][m][r] + bb[0])*(1.f - ti) + ti*fast_tanh(ac[1][m][r] + bb[1]);
            hbuf[wave][m*16 + (lane>>4)*4 + r][r0] = f2h_bits(hv);
          }
        }
      }
      __syncthreads();                       // barC (c_t complete in hbuf)
      { // y_t = c_t @ Wout^T + bout
        #pragma unroll
        for (int m = 0; m < 4; ++m) {
          f32x4 acc = {0.f,0.f,0.f,0.f};
          #pragma unroll
          for (int kk = 0; kk < 2; ++kk) {
            int k0 = kk*32 + ks;
            f16x8 a = __builtin_bit_cast(f16x8, *(const u16x8*)&hbuf[k0 >> 4][m*16 + r0][k0 & 15]);
            acc = MFMA16(a, woutf[kk], acc);
          }
          int rb = (lane >> 4) * 4;
          #pragma unroll
          for (int r = 0; r < 4; ++r) {
            int row = m*16 + rb + r;
            out[((size_t)(b0 + row) * LSEQ + t) * 64 + tile*16 + r0] = acc[r] + bov;
          }
        }
      }
    }
  }
}

extern "C" void kernel_launch(void* const* d_in, const int* in_sizes, int n_in,
                              void* d_out, int out_size, void* d_ws, size_t ws_size,
                              hipStream_t stream) {
  const float* dt   = (const float*)d_in[0];
  const float* hs   = (const float*)d_in[1];
  const float* W0   = (const float*)d_in[2];
  const float* b0v  = (const float*)d_in[3];
  const float* W1   = (const float*)d_in[4];
  const float* b1v  = (const float*)d_in[5];
  const float* W2   = (const float*)d_in[6];
  const float* b2v  = (const float*)d_in[7];
  const float* Wo   = (const float*)d_in[8];
  const float* bo   = (const float*)d_in[9];
  const float* M0   = (const float*)d_in[10];
  const float* M1   = (const float*)d_in[11];
  const float* M2   = (const float*)d_in[12];
  (void)in_sizes; (void)n_in; (void)out_size; (void)ws_size;
  init_state<<<8, 256, 0, stream>>>(hs, (char*)d_ws);
  rnn_persist<<<72, 256, 0, stream>>>(dt, W0, b0v, W1, b1v, W2, b2v, Wo, bo, M0, M1, M2,
                                      (float*)d_out, (char*)d_ws);
}

// Round 14
// 1037.541 us; speedup vs baseline: 2.4443x; 1.8525x over previous
//
#include <hip/hip_runtime.h>
#include <stdint.h>

typedef _Float16 f16x8 __attribute__((ext_vector_type(8)));
typedef unsigned short u16x8 __attribute__((ext_vector_type(8)));
typedef float f32x4 __attribute__((ext_vector_type(4)));
typedef unsigned int u32x4 __attribute__((ext_vector_type(4)));

#define MFMA16(a,b,c) __builtin_amdgcn_mfma_f32_16x16x32_f16((a),(b),(c),0,0,0)

// problem dims
#define LSEQ 256
#define H0N  269
#define H1N  179
#define H0P  272
#define H1P  192
#define K0REAL 333
#define K1REAL 448
#define K2REAL 243
#define KK0  11    // cell0 K padded to 352
#define KK1  15    // cell1 K padded to 480 ([a:272|b:192pad])
#define KK2  8     // cell2 [b:192|c:64(hbuf)]
#define XH0S 360
#define XH1S 488
#define XH2S 200
#define MR   32

// ws layout per group (bytes)
#define H0_OFF   0
#define H0_SLOT  (MR*H0P*2)            // 17408
#define H1_OFF   (8*H0_SLOT)           // 139264
#define H1_SLOT  (MR*H1P*2)            // 12288
#define C2_OFF   (H1_OFF + 8*H1_SLOT)  // 237568 (c_{-1} init slot)
#define CNT_OFF  (C2_OFF + 4096)       // 9 per-WG guard flags
#define GSTRIDE  262144

#define BIGNEG   (-(1<<28))
#define NQ0 5
#define NQ1 8
#define NQ2 3

__device__ __forceinline__ unsigned short f2h_bits(float v) {
  return __builtin_bit_cast(unsigned short, (_Float16)v);
}
__device__ __forceinline__ float rcpf(float x) { return __builtin_amdgcn_rcpf(x); }
__device__ __forceinline__ float fast_sig(float s) { return rcpf(1.f + __expf(-s)); }
__device__ __forceinline__ float fast_tanh(float x) {
  float e = __expf(2.f * x);
  return 1.f - 2.f * rcpf(e + 1.f);
}

// ---- MALL-coherent (sc0 sc1) ops — the only HW-proven cross-WG path ----
__device__ __forceinline__ u16x8 ldg16s(const unsigned short* p) {
  u16x8 r;
  asm volatile("global_load_dwordx4 %0, %1, off sc0 sc1" : "=v"(r) : "v"(p));
  return r;
}
__device__ __forceinline__ void stg16s(unsigned short* p, u16x8 v) {
  asm volatile("global_store_dwordx4 %0, %1, off sc0 sc1" :: "v"(p), "v"(v) : "memory");
}
__device__ __forceinline__ unsigned ld_flag(const unsigned int* p) {
  unsigned v;
  asm volatile("global_load_dword %0, %1, off sc0 sc1" : "=v"(v) : "v"(p) : "memory");
  return v;
}
__device__ __forceinline__ void st_flag(unsigned int* p, unsigned v) {
  asm volatile("global_store_dword %0, %1, off sc0 sc1" :: "v"(p), "v"(v) : "memory");
}
#define VM_WAIT0 do { asm volatile("s_waitcnt vmcnt(0)" ::: "memory"); __builtin_amdgcn_sched_barrier(0); } while (0)

// ---- step tags in fp16 mantissa bit0: tag(s) = ((s+8)>>3)&1 (flips per ring lap) ----
__device__ __forceinline__ bool chunk_fresh(u16x8 v, unsigned tp) {
  u32x4 d = __builtin_bit_cast(u32x4, v);
  return ((d[0] & 0x00010001u) == tp) & ((d[1] & 0x00010001u) == tp) &
         ((d[2] & 0x00010001u) == tp) & ((d[3] & 0x00010001u) == tp);
}
__device__ __forceinline__ u16x8 tag_chunk(u16x8 v, unsigned tp) {
  u32x4 d = __builtin_bit_cast(u32x4, v);
  d &= 0xFFFEFFFEu;
  d |= tp;
  return __builtin_bit_cast(u16x8, d);
}

// ---------------- init: scrub rings to tag-0, write t=-1 state (tag 0) ----------------
__global__ void __launch_bounds__(256) init_state(const float* __restrict__ hs, char* __restrict__ ws) {
  int g = blockIdx.x, tid = threadIdx.x;
  char* gb = ws + (size_t)g * GSTRIDE;
  uint4 z4 = {0,0,0,0};
  int total16 = (CNT_OFF + 512) / 16;
  for (int i = tid; i < total16; i += 256) ((uint4*)gb)[i] = z4;   // rings zeroed -> tag 0
  __syncthreads();
  int b0 = g * MR;
  unsigned short* H0 = (unsigned short*)(gb + H0_OFF + 7*(size_t)H0_SLOT);
  unsigned short* H1 = (unsigned short*)(gb + H1_OFF + 7*(size_t)H1_SLOT);
  unsigned short* C2 = (unsigned short*)(gb + C2_OFF);
  for (int i = tid; i < MR*H0P; i += 256) { int r = i/H0P, c = i%H0P;
    H0[i] = (c < H0N) ? (unsigned short)(f2h_bits(hs[(size_t)(b0+r)*512 + c]) & 0xFFFEu) : (unsigned short)0; }
  for (int i = tid; i < MR*H1P; i += 256) { int r = i/H1P, c = i%H1P;
    H1[i] = (c < H1N) ? (unsigned short)(f2h_bits(hs[(size_t)(b0+r)*512 + H0N + c]) & 0xFFFEu) : (unsigned short)0; }
  for (int i = tid; i < MR*64;  i += 256) { int r = i>>6,  c = i&63;
    C2[i] = f2h_bits(hs[(size_t)(b0+r)*512 + 448 + c]); }
}

// ---------------- weight fragment builder, 3 gates (gate2 = W_ta + W_tb) ----------------
template<int KK, int MODE>
__device__ __forceinline__ void build_frag3(f16x8* wf, const float* __restrict__ W, const float* __restrict__ Msk,
                                            int h, int Kreal, int g4, int tile, int lane) {
  int col = tile * 16 + (lane & 15);
  bool nv = (col < h);
  #pragma unroll
  for (int kk = 0; kk < KK; ++kk) {
    f16x8 s;
    #pragma unroll
    for (int e = 0; e < 8; ++e) {
      int k = kk*32 + ((lane >> 4) << 3) + e;
      int wc;
      if (MODE == 0)      wc = (k < 333) ? k : -1;
      else if (MODE == 1) wc = (k < 269) ? k : ((k >= 272 && k < 451) ? (k - 3) : -1);
      else                wc = (k < 179) ? k : ((k >= 192 && k < 256) ? (k - 13) : -1);
      float val = 0.f;
      if (nv && wc >= 0) {
        if (g4 < 2) val = W[(size_t)(g4 * h + col) * Kreal + wc] * Msk[(size_t)col * Kreal + wc];
        else        val = W[(size_t)(2 * h + col) * Kreal + wc] + W[(size_t)(3 * h + col) * Kreal + wc];
      }
      s[e] = (_Float16)val;
    }
    wf[kk] = s;
  }
}

__device__ __forceinline__ f16x8 lda(const unsigned short* xh, int stride, int mt, int kk, int lane) {
  const unsigned short* p = xh + (size_t)(mt*16 + (lane & 15)) * stride + kk*32 + ((lane >> 4) << 3);
  return __builtin_bit_cast(f16x8, *(const u16x8*)p);
}

// ---------------- persistent cascade kernel (r9 protocol + dbuf LDS, 1 barrier/step) ----------------
// 16 groups x 9 WGs. j=0..4 cell0 (tile=j*4+wave, 17 active waves); j=5..7 cell1
// (12 waves); j=8 cell2+y. WG-coalesced staging polls (data-as-flag, mantissa-bit0
// step tags). Guard flags cnt[0..8]: cnt[wg]=t+1 after wg finished STAGING step t.
// Ring guards: cell0@t needs cnt[0..4]>=t-6, cnt[5..7]>=t-7; cell1@t needs
// cnt[5..7]>=t-6, cnt[8]>=t-7. xhS double-buffered (t&1) -> post-MFMA barrier
// deleted in cells 0/1: next step's staging writes the other buffer while
// laggard waves still read this one.
__global__ void __launch_bounds__(256, 1) rnn_persist(
    const float* __restrict__ dt,
    const float* __restrict__ W0, const float* __restrict__ b0v,
    const float* __restrict__ W1, const float* __restrict__ b1v,
    const float* __restrict__ W2, const float* __restrict__ b2v,
    const float* __restrict__ Wout, const float* __restrict__ boutg,
    const float* __restrict__ M0, const float* __restrict__ M1, const float* __restrict__ M2,
    float* __restrict__ out, char* __restrict__ ws)
{
  __shared__ __attribute__((aligned(16))) unsigned short xhS[2][MR * XH1S]; // 2x31232 B
  __shared__ __attribute__((aligned(16))) unsigned short hbuf[4][MR][16];   // 4 KB

  int tid = threadIdx.x;
  int lane = tid & 63, wave = tid >> 6;
  int bid = blockIdx.x;
  int j = bid >> 4;
  int g = bid & 15;
  int b0 = g * MR;

  char* gb = ws + (size_t)g * GSTRIDE;
  unsigned short* H0r = (unsigned short*)(gb + H0_OFF);
  unsigned short* H1r = (unsigned short*)(gb + H1_OFF);
  unsigned int*   cnt = (unsigned int*)(gb + CNT_OFF);
  int r0 = lane & 15;
  u16x8 zz = {0,0,0,0,0,0,0,0};

  if (j < 5) {
    // ================= cell0 =================
    int tile = j*4 + wave;
    bool act = (tile < 17);
    int ncol = tile*16 + r0;
    bool cok = act && (ncol < H0N);
    f16x8 wf[3][KK0];
    if (act) {
      #pragma unroll
      for (int g4 = 0; g4 < 3; ++g4) build_frag3<KK0,0>(wf[g4], W0, M0, H0N, K0REAL, g4, tile, lane);
    }
    float bb[3] = {0.f,0.f,0.f};
    if (cok) {
      bb[0] = b0v[ncol]; bb[1] = b0v[H0N + ncol];
      bb[2] = b0v[2*H0N + ncol] + b0v[3*H0N + ncol];
    }
    if (tid < 128) {  // static k-pad 336..351, both buffers
      int r = (tid & 63) >> 1, c8 = 336 + (tid & 1)*8;
      *(u16x8*)(&xhS[tid >> 6][(size_t)r*XH0S + c8]) = zz;
    }
    int aoff[NQ0], adst[NQ0]; bool aval[NQ0];
    #pragma unroll
    for (int q = 0; q < NQ0; ++q) {
      int idx = tid + q*256;
      aval[q] = (idx < MR*34);
      int r = idx / 34, cc = (idx % 34) * 8;
      aoff[q] = r*H0P + cc;
      adst[q] = r*XH0S + 64 + cc;
    }
    int xrow = tid >> 3, xc = (tid & 7) * 8;
    const float* dtb = dt + ((size_t)(b0 + xrow) * LSEQ) * 64 + xc;
    float4 xA = *(const float4*)(dtb);
    float4 xB = *(const float4*)(dtb + 4);
    int goff = (lane < 5) ? -6 : (lane < 8) ? -7 : BIGNEG;
    __syncthreads();   // k-pad of both buffers visible
    for (int t = 0; t < LSEQ; ++t) {
      unsigned short* xb = xhS[t & 1];
      unsigned tpm1 = (((unsigned)(t + 7) >> 3) & 1) * 0x00010001u;  // tag a_{t-1}
      unsigned tpt  = (((unsigned)(t + 8) >> 3) & 1) * 0x00010001u;  // tag a_t
      { // write x_t from prefetched regs
        unsigned short* d = xb + (size_t)xrow*XH0S + xc;
        d[0]=f2h_bits(xA.x); d[1]=f2h_bits(xA.y); d[2]=f2h_bits(xA.z); d[3]=f2h_bits(xA.w);
        d[4]=f2h_bits(xB.x); d[5]=f2h_bits(xB.y); d[6]=f2h_bits(xB.z); d[7]=f2h_bits(xB.w);
      }
      // tag-poll a_{t-1} (WG-coalesced; the poll IS the read) + ring guards
      const unsigned short* H0s = H0r + (size_t)((t + 7) & 7) * (MR*H0P);
      u16x8 tA[NQ0];
      for (int it = 0; it < (1 << 17); ++it) {
        unsigned gv = 0;
        if (lane < 8) gv = ld_flag(cnt + lane);
        #pragma unroll
        for (int q = 0; q < NQ0; ++q) if (aval[q]) tA[q] = ldg16s(H0s + aoff[q]);
        VM_WAIT0;
        bool ok = ((int)gv >= t + goff);
        #pragma unroll
        for (int q = 0; q < NQ0; ++q) if (aval[q]) ok &= chunk_fresh(tA[q], tpm1);
        if (__all(ok)) break;
        if (it >= 4) __builtin_amdgcn_s_sleep(1);
      }
      #pragma unroll
      for (int q = 0; q < NQ0; ++q) if (aval[q]) *(u16x8*)(xb + adst[q]) = tA[q];
      __syncthreads();                       // barA (only barrier this step)
      if (tid == 0) st_flag(&cnt[j], t + 1); // staging done -> release a-ring slot
      { int tn = (t + 1 < LSEQ) ? t + 1 : t; // prefetch x(t+1) under MFMA
        xA = *(const float4*)(dtb + (size_t)tn*64);
        xB = *(const float4*)(dtb + (size_t)tn*64 + 4); }
      f32x4 ac[3][2];
      if (act) {
        #pragma unroll
        for (int g4 = 0; g4 < 3; ++g4) { ac[g4][0] = (f32x4){0,0,0,0}; ac[g4][1] = (f32x4){0,0,0,0}; }
        #pragma unroll
        for (int kk = 0; kk < KK0; ++kk) {
          f16x8 a0 = lda(xb, XH0S, 0, kk, lane);
          f16x8 a1 = lda(xb, XH0S, 1, kk, lane);
          #pragma unroll
          for (int g4 = 0; g4 < 3; ++g4) {
            ac[g4][0] = MFMA16(a0, wf[g4][kk], ac[g4][0]);
            ac[g4][1] = MFMA16(a1, wf[g4][kk], ac[g4][1]);
          }
        }
        #pragma unroll
        for (int m = 0; m < 2; ++m) {
          #pragma unroll
          for (int r = 0; r < 4; ++r) {
            float ti = fast_sig(ac[2][m][r] + bb[2]);
            float hv = cok ? (fast_tanh(ac[0][m][r] + bb[0])*(1.f - ti) + ti*fast_tanh(ac[1][m][r] + bb[1])) : 0.f;
            hbuf[wave][m*16 + (lane>>4)*4 + r][r0] = f2h_bits(hv);
          }
        }
        int srow = lane >> 1, c8v = (lane & 1) * 8;
        u16x8 hv8 = tag_chunk(*(const u16x8*)&hbuf[wave][srow][c8v], tpt);
        unsigned short* Hn = H0r + (size_t)(t & 7) * (MR*H0P);
        stg16s(Hn + (size_t)srow*H0P + tile*16 + c8v, hv8);   // tagged store IS the flag
      }
    }
  } else if (j < 8) {
    // ================= cell1 =================
    int tile = (j - 5)*4 + wave;
    int ncol = tile*16 + r0;
    bool cok = (ncol < H1N);
    f16x8 wf[3][KK1];
    #pragma unroll
    for (int g4 = 0; g4 < 3; ++g4) build_frag3<KK1,1>(wf[g4], W1, M1, H1N, K1REAL, g4, tile, lane);
    float bb[3] = {0.f,0.f,0.f};
    if (cok) {
      bb[0] = b1v[ncol]; bb[1] = b1v[H1N + ncol];
      bb[2] = b1v[2*H1N + ncol] + b1v[3*H1N + ncol];
    }
    if (tid < 128) {  // static k-pad 464..479, both buffers
      int r = (tid & 63) >> 1, c8 = 464 + (tid & 1)*8;
      *(u16x8*)(&xhS[tid >> 6][(size_t)r*XH1S + c8]) = zz;
    }
    int soff[NQ1], sdst[NQ1]; bool sval[NQ1], sisB[NQ1];
    #pragma unroll
    for (int q = 0; q < NQ1; ++q) {
      int idx = tid + q*256;
      if (idx < 1088) {
        sval[q] = true; sisB[q] = false;
        int r = idx / 34, cc = (idx % 34) * 8;
        soff[q] = r*H0P + cc; sdst[q] = r*XH1S + cc;
      } else {
        int i2 = idx - 1088;
        sval[q] = (i2 < 768); sisB[q] = true;
        int r = i2 / 24, cc = (i2 % 24) * 8;
        soff[q] = r*H1P + cc; sdst[q] = r*XH1S + 272 + cc;
      }
    }
    int goff = (lane >= 5 && lane < 8) ? -6 : (lane == 8) ? -7 : BIGNEG;
    __syncthreads();
    for (int t = 0; t < LSEQ; ++t) {
      unsigned short* xb = xhS[t & 1];
      unsigned tpm1 = (((unsigned)(t + 7) >> 3) & 1) * 0x00010001u;  // b_{t-1}
      unsigned tpt  = (((unsigned)(t + 8) >> 3) & 1) * 0x00010001u;  // a_t / b_t
      const unsigned short* As = H0r + (size_t)(t & 7) * (MR*H0P);
      const unsigned short* Bs = H1r + (size_t)((t + 7) & 7) * (MR*H1P);
      u16x8 tS[NQ1];
      for (int it = 0; it < (1 << 17); ++it) {
        unsigned gv = 0;
        if (lane >= 5 && lane < 9) gv = ld_flag(cnt + lane);
        #pragma unroll
        for (int q = 0; q < NQ1; ++q) if (sval[q]) tS[q] = ldg16s((sisB[q] ? Bs : As) + soff[q]);
        VM_WAIT0;
        bool ok = ((int)gv >= t + goff);
        #pragma unroll
        for (int q = 0; q < NQ1; ++q) {
          if (sval[q]) ok &= chunk_fresh(tS[q], sisB[q] ? tpm1 : tpt);
        }
        if (__all(ok)) break;
        if (it >= 4) __builtin_amdgcn_s_sleep(1);
      }
      #pragma unroll
      for (int q = 0; q < NQ1; ++q) if (sval[q]) *(u16x8*)(xb + sdst[q]) = tS[q];
      __syncthreads();                       // barA
      if (tid == 0) st_flag(&cnt[j], t + 1);
      f32x4 ac[3][2];
      #pragma unroll
      for (int g4 = 0; g4 < 3; ++g4) { ac[g4][0] = (f32x4){0,0,0,0}; ac[g4][1] = (f32x4){0,0,0,0}; }
      #pragma unroll
      for (int kk = 0; kk < KK1; ++kk) {
        f16x8 a0 = lda(xb, XH1S, 0, kk, lane);
        f16x8 a1 = lda(xb, XH1S, 1, kk, lane);
        #pragma unroll
        for (int g4 = 0; g4 < 3; ++g4) {
          ac[g4][0] = MFMA16(a0, wf[g4][kk], ac[g4][0]);
          ac[g4][1] = MFMA16(a1, wf[g4][kk], ac[g4][1]);
        }
      }
      #pragma unroll
      for (int m = 0; m < 2; ++m) {
        #pragma unroll
        for (int r = 0; r < 4; ++r) {
          float ti = fast_sig(ac[2][m][r] + bb[2]);
          float hv = cok ? (fast_tanh(ac[0][m][r] + bb[0])*(1.f - ti) + ti*fast_tanh(ac[1][m][r] + bb[1])) : 0.f;
          hbuf[wave][m*16 + (lane>>4)*4 + r][r0] = f2h_bits(hv);
        }
      }
      int srow = lane >> 1, c8v = (lane & 1) * 8;
      u16x8 hv8 = tag_chunk(*(const u16x8*)&hbuf[wave][srow][c8v], tpt);
      unsigned short* Hn = H1r + (size_t)(t & 7) * (MR*H1P);
      stg16s(Hn + (size_t)srow*H1P + tile*16 + c8v, hv8);
    }
  } else {
    // ================= cell2 + y (c-state in hbuf; intra-WG) =================
    int tile = wave;
    int ncol = tile*16 + r0;
    int ks = (lane >> 4) * 8;
    f16x8 wf[3][KK2], woutf[2];
    #pragma unroll
    for (int g4 = 0; g4 < 3; ++g4) build_frag3<KK2,2>(wf[g4], W2, M2, 64, K2REAL, g4, tile, lane);
    {
      #pragma unroll
      for (int kk = 0; kk < 2; ++kk) {
        f16x8 s;
        #pragma unroll
        for (int e = 0; e < 8; ++e) {
          int k = kk*32 + ks + e;
          s[e] = (_Float16)Wout[(size_t)ncol*64 + k];
        }
        woutf[kk] = s;
      }
    }
    float bov = boutg[ncol];
    float bb[3];
    bb[0] = b2v[ncol]; bb[1] = b2v[64 + ncol];
    bb[2] = b2v[2*64 + ncol] + b2v[3*64 + ncol];
    { // preload c_{-1}
      const unsigned short* C2i = (const unsigned short*)(gb + C2_OFF);
      int r = tid >> 3, c8 = (tid & 7) * 8;
      u16x8 cv = ldg16s(C2i + r*64 + c8);
      VM_WAIT0;
      *(u16x8*)&hbuf[c8 >> 4][r][c8 & 15] = cv;
    }
    int soff[NQ2], sdst[NQ2];
    #pragma unroll
    for (int q = 0; q < NQ2; ++q) {
      int idx = tid + q*256;
      int r = idx / 24, cc = (idx % 24) * 8;
      soff[q] = r*H1P + cc; sdst[q] = r*XH2S + cc;
    }
    for (int t = 0; t < LSEQ; ++t) {
      unsigned short* xb = xhS[t & 1];
      unsigned tpt = (((unsigned)(t + 8) >> 3) & 1) * 0x00010001u;  // b_t
      const unsigned short* Bs = H1r + (size_t)(t & 7) * (MR*H1P);
      u16x8 tS[NQ2];
      for (int it = 0; it < (1 << 17); ++it) {
        #pragma unroll
        for (int q = 0; q < NQ2; ++q) tS[q] = ldg16s(Bs + soff[q]);
        VM_WAIT0;
        bool ok = true;
        #pragma unroll
        for (int q = 0; q < NQ2; ++q) ok &= chunk_fresh(tS[q], tpt);
        if (__all(ok)) break;
        if (it >= 4) __builtin_amdgcn_s_sleep(1);
      }
      #pragma unroll
      for (int q = 0; q < NQ2; ++q) *(u16x8*)(xb + sdst[q]) = tS[q];
      __syncthreads();                       // barA
      if (tid == 0) st_flag(&cnt[8], t + 1); // b_t consumed -> release b-ring slot
      f32x4 ac[3][2];
      #pragma unroll
      for (int g4 = 0; g4 < 3; ++g4) { ac[g4][0] = (f32x4){0,0,0,0}; ac[g4][1] = (f32x4){0,0,0,0}; }
      #pragma unroll
      for (int kk = 0; kk < KK2; ++kk) {
        f16x8 a0, a1;
        if (kk < 6) {
          a0 = lda(xb, XH2S, 0, kk, lane);
          a1 = lda(xb, XH2S, 1, kk, lane);
        } else {  // c_{t-1} from hbuf
          int k0 = kk*32 + ks - 192;
          a0 = __builtin_bit_cast(f16x8, *(const u16x8*)&hbuf[k0 >> 4][r0][k0 & 15]);
          a1 = __builtin_bit_cast(f16x8, *(const u16x8*)&hbuf[k0 >> 4][16 + r0][k0 & 15]);
        }
        #pragma unroll
        for (int g4 = 0; g4 < 3; ++g4) {
          ac[g4][0] = MFMA16(a0, wf[g4][kk], ac[g4][0]);
          ac[g4][1] = MFMA16(a1, wf[g4][kk], ac[g4][1]);
        }
      }
      __syncthreads();                       // barB (hbuf c_{t-1} reads done)
      {
        #pragma unroll
        for (int m = 0; m < 2; ++m) {
          #pragma unroll
          for (int r = 0; r < 4; ++r) {
            float ti = fast_sig(ac[2][m][r] + bb[2]);
            float hv = fast_tanh(ac[0][m][r] + bb[0])*(1.f - ti) + ti*fast_tanh(ac[1][m][r] + bb[1]);
            hbuf[wave][m*16 + (lane>>4)*4 + r][r0] = f2h_bits(hv);
          }
        }
      }
      __syncthreads();                       // barC (c_t complete in hbuf)
      { // y_t = c_t @ Wout^T + bout
        #pragma unroll
        for (int m = 0; m < 2; ++m) {
          f32x4 acc = {0.f,0.f,0.f,0.f};
          #pragma unroll
          for (int kk = 0; kk < 2; ++kk) {
            int k0 = kk*32 + ks;
            f16x8 a = __builtin_bit_cast(f16x8, *(const u16x8*)&hbuf[k0 >> 4][m*16 + r0][k0 & 15]);
            acc = MFMA16(a, woutf[kk], acc);
          }
          int rb = (lane >> 4) * 4;
          #pragma unroll
          for (int r = 0; r < 4; ++r) {
            int row = m*16 + rb + r;
            out[((size_t)(b0 + row) * LSEQ + t) * 64 + tile*16 + r0] = acc[r] + bov;
          }
        }
      }
    }
  }
}

extern "C" void kernel_launch(void* const* d_in, const int* in_sizes, int n_in,
                              void* d_out, int out_size, void* d_ws, size_t ws_size,
                              hipStream_t stream) {
  const float* dt   = (const float*)d_in[0];
  const float* hs   = (const float*)d_in[1];
  const float* W0   = (const float*)d_in[2];
  const float* b0v  = (const float*)d_in[3];
  const float* W1   = (const float*)d_in[4];
  const float* b1v  = (const float*)d_in[5];
  const float* W2   = (const float*)d_in[6];
  const float* b2v  = (const float*)d_in[7];
  const float* Wo   = (const float*)d_in[8];
  const float* bo   = (const float*)d_in[9];
  const float* M0   = (const float*)d_in[10];
  const float* M1   = (const float*)d_in[11];
  const float* M2   = (const float*)d_in[12];
  (void)in_sizes; (void)n_in; (void)out_size; (void)ws_size;
  init_state<<<16, 256, 0, stream>>>(hs, (char*)d_ws);
  rnn_persist<<<144, 256, 0, stream>>>(dt, W0, b0v, W1, b1v, W2, b2v, Wo, bo, M0, M1, M2,
                                       (float*)d_out, (char*)d_ws);
}